// Round 1
// baseline (533.852 us; speedup 1.0000x reference)
//
#include <hip/hip_runtime.h>
#include <hip/hip_bf16.h>

typedef __bf16 bf16;
typedef bf16 bf16x8 __attribute__((ext_vector_type(8)));
typedef float floatx4 __attribute__((ext_vector_type(4)));

#define MFMA_BF16(a, b, c) __builtin_amdgcn_mfma_f32_16x16x32_bf16((a), (b), (c), 0, 0, 0)

// ---------------------------------------------------------------------------
// GEMM 1: Q = x @ Wq   (A[4096,1024] fp32, W[1024,1024] fp32 -> Qbf[4096,1024] bf16)
// 64x64 tile, BK=32, 256 threads (4 waves), wave computes 16x64 strip.
// ---------------------------------------------------------------------------
__global__ __launch_bounds__(256) void gemm_q(const float* __restrict__ A,
                                              const float* __restrict__ W,
                                              bf16* __restrict__ C) {
    __shared__ bf16 As[64 * 40];  // [m][k] padded 32->40
    __shared__ bf16 Bs[64 * 40];  // [n][k] transposed, padded
    const int t = threadIdx.x;
    const int wv = t >> 6, lane = t & 63, quad = lane >> 4, l15 = lane & 15;
    const int m0 = blockIdx.y * 64, n0 = blockIdx.x * 64;
    const int N = 1024;

    floatx4 acc[4] = {{0.f,0.f,0.f,0.f},{0.f,0.f,0.f,0.f},{0.f,0.f,0.f,0.f},{0.f,0.f,0.f,0.f}};

    for (int k0 = 0; k0 < 1024; k0 += 32) {
        // stage A tile 64x32 (8 fp32 per thread)
        {
            int r = t >> 2, c = (t & 3) * 8;
            const float* src = A + (size_t)(m0 + r) * 1024 + k0 + c;
            float4 f0 = *(const float4*)src;
            float4 f1 = *(const float4*)(src + 4);
            bf16x8 v = {(bf16)f0.x, (bf16)f0.y, (bf16)f0.z, (bf16)f0.w,
                        (bf16)f1.x, (bf16)f1.y, (bf16)f1.z, (bf16)f1.w};
            *(bf16x8*)&As[r * 40 + c] = v;
        }
        // stage B tile 32x64 transposed into Bs[n][k]
        {
            int kr = t >> 3, c = (t & 7) * 8;
            const float* src = W + (size_t)(k0 + kr) * N + n0 + c;
            float4 f0 = *(const float4*)src;
            float4 f1 = *(const float4*)(src + 4);
            float f[8] = {f0.x, f0.y, f0.z, f0.w, f1.x, f1.y, f1.z, f1.w};
#pragma unroll
            for (int u = 0; u < 8; ++u) Bs[(c + u) * 40 + kr] = (bf16)f[u];
        }
        __syncthreads();
        bf16x8 a = *(bf16x8*)&As[(wv * 16 + l15) * 40 + quad * 8];
#pragma unroll
        for (int nt = 0; nt < 4; ++nt) {
            bf16x8 b = *(bf16x8*)&Bs[(nt * 16 + l15) * 40 + quad * 8];
            acc[nt] = MFMA_BF16(a, b, acc[nt]);
        }
        __syncthreads();
    }
#pragma unroll
    for (int nt = 0; nt < 4; ++nt)
#pragma unroll
        for (int r = 0; r < 4; ++r) {
            int m = m0 + wv * 16 + quad * 4 + r;
            int n = n0 + nt * 16 + l15;
            C[(size_t)m * N + n] = (bf16)acc[nt][r];
        }
}

// ---------------------------------------------------------------------------
// GEMM 2: KV = context @ Wkv  (A[4096,1024], W[1024,2048])
// n<1024 -> Kbf[4096,1024]; n>=1024 -> Vt[b][h][d][j] (V transposed per head)
// ---------------------------------------------------------------------------
__global__ __launch_bounds__(256) void gemm_kv(const float* __restrict__ A,
                                               const float* __restrict__ W,
                                               bf16* __restrict__ Kb,
                                               bf16* __restrict__ Vt) {
    __shared__ bf16 As[64 * 40];
    __shared__ bf16 Bs[64 * 40];
    const int t = threadIdx.x;
    const int wv = t >> 6, lane = t & 63, quad = lane >> 4, l15 = lane & 15;
    const int m0 = blockIdx.y * 64, n0 = blockIdx.x * 64;
    const int N = 2048;

    floatx4 acc[4] = {{0.f,0.f,0.f,0.f},{0.f,0.f,0.f,0.f},{0.f,0.f,0.f,0.f},{0.f,0.f,0.f,0.f}};

    for (int k0 = 0; k0 < 1024; k0 += 32) {
        {
            int r = t >> 2, c = (t & 3) * 8;
            const float* src = A + (size_t)(m0 + r) * 1024 + k0 + c;
            float4 f0 = *(const float4*)src;
            float4 f1 = *(const float4*)(src + 4);
            bf16x8 v = {(bf16)f0.x, (bf16)f0.y, (bf16)f0.z, (bf16)f0.w,
                        (bf16)f1.x, (bf16)f1.y, (bf16)f1.z, (bf16)f1.w};
            *(bf16x8*)&As[r * 40 + c] = v;
        }
        {
            int kr = t >> 3, c = (t & 7) * 8;
            const float* src = W + (size_t)(k0 + kr) * N + n0 + c;
            float4 f0 = *(const float4*)src;
            float4 f1 = *(const float4*)(src + 4);
            float f[8] = {f0.x, f0.y, f0.z, f0.w, f1.x, f1.y, f1.z, f1.w};
#pragma unroll
            for (int u = 0; u < 8; ++u) Bs[(c + u) * 40 + kr] = (bf16)f[u];
        }
        __syncthreads();
        bf16x8 a = *(bf16x8*)&As[(wv * 16 + l15) * 40 + quad * 8];
#pragma unroll
        for (int nt = 0; nt < 4; ++nt) {
            bf16x8 b = *(bf16x8*)&Bs[(nt * 16 + l15) * 40 + quad * 8];
            acc[nt] = MFMA_BF16(a, b, acc[nt]);
        }
        __syncthreads();
    }
#pragma unroll
    for (int nt = 0; nt < 4; ++nt)
#pragma unroll
        for (int r = 0; r < 4; ++r) {
            int m = m0 + wv * 16 + quad * 4 + r;
            int n = n0 + nt * 16 + l15;
            bf16 v = (bf16)acc[nt][r];
            if (n < 1024) {
                Kb[(size_t)m * 1024 + n] = v;
            } else {
                int h = (n - 1024) >> 6, d = (n - 1024) & 63;
                int bb = m >> 10, j = m & 1023;
                Vt[(size_t)((bb * 16 + h) * 64 + d) * 1024 + j] = v;
            }
        }
}

// ---------------------------------------------------------------------------
// Fused attention: one workgroup per (b, 16-query tile). 512 threads = 8 waves,
// 2 heads per wave. Two passes: (1) softmax denominators, (2) per 32-wide
// j-tile: S (MFMA) -> w=exp*invl -> LDS -> talking-heads mix (MFMA, k zero-
// padded 16->32) -> LN over heads (quad shuffles) -> PV (MFMA, Vt from global).
// ---------------------------------------------------------------------------
__global__ __launch_bounds__(512) void attn_kernel(const bf16* __restrict__ Qb,
                                                   const bf16* __restrict__ Kb,
                                                   const bf16* __restrict__ Vt,
                                                   const float* __restrict__ Wt,
                                                   const float* __restrict__ gamma,
                                                   const float* __restrict__ beta,
                                                   float* __restrict__ out) {
    // LDS: Buf1[point p=i*32+jl][40 slots: h(0..15), zeros(16..31), pad]   = 40 KB
    //      Buf2[g][i][jl] bf16, strides 648 / 40                            = 20.25 KB
    //      mlL  invl per [h][i]                                             = 1 KB
    __shared__ bf16 Buf1[512 * 40];
    __shared__ bf16 Buf2[16 * 648];
    __shared__ float mlL[16 * 16];

    const int t = threadIdx.x;
    const int wv = t >> 6, lane = t & 63, quad = lane >> 4, l15 = lane & 15;
    const int b = blockIdx.y, i0 = blockIdx.x * 16;
    const int h0 = wv * 2;
    const float scale = 0.125f;  // 1/sqrt(64)

    // zero the padded h-slots (16..31) of Buf1 once; never rewritten
    {
        bf16x8 z = {(bf16)0.f,(bf16)0.f,(bf16)0.f,(bf16)0.f,(bf16)0.f,(bf16)0.f,(bf16)0.f,(bf16)0.f};
        *(bf16x8*)&Buf1[t * 40 + 16] = z;
        *(bf16x8*)&Buf1[t * 40 + 24] = z;
    }

    // Wt B-fragment (constant): B[k=quad*8+jj][n=l15], zero-padded k>=16
    bf16x8 wtf;
#pragma unroll
    for (int jj = 0; jj < 8; ++jj) {
        int h = quad * 8 + jj;
        wtf[jj] = (h < 16) ? (bf16)Wt[h * 16 + l15] : (bf16)0.f;
    }
    const float gamma_l = gamma[l15];
    const float beta_l = beta[l15];

    // Q fragments: lane l15 = query row i; per head h: k=d in [0,64) -> 2 frags
    bf16x8 qa[2][2];
#pragma unroll
    for (int hh = 0; hh < 2; ++hh) {
        const bf16* qp = Qb + (size_t)(b * 1024 + i0 + l15) * 1024 + (h0 + hh) * 64 + quad * 8;
        qa[hh][0] = *(const bf16x8*)qp;
        qa[hh][1] = *(const bf16x8*)(qp + 32);
    }

    const bf16* Kbase = Kb + (size_t)b * 1024 * 1024;
    const bf16* Vbase = Vt + (size_t)b * 16 * 64 * 1024;

    // ---- pass 1: softmax denominators (no max subtraction; s ~ N(0,1)) ----
#pragma unroll
    for (int hh = 0; hh < 2; ++hh) {
        int h = h0 + hh;
        float se[4] = {0.f, 0.f, 0.f, 0.f};
        for (int jt = 0; jt < 64; ++jt) {
            const bf16* kp = Kbase + (size_t)(jt * 16 + l15) * 1024 + h * 64 + quad * 8;
            bf16x8 b0 = *(const bf16x8*)kp;
            bf16x8 b1 = *(const bf16x8*)(kp + 32);
            floatx4 c = {0.f, 0.f, 0.f, 0.f};
            c = MFMA_BF16(qa[hh][0], b0, c);
            c = MFMA_BF16(qa[hh][1], b1, c);
#pragma unroll
            for (int r = 0; r < 4; ++r) se[r] += __expf(c[r] * scale);
        }
#pragma unroll
        for (int r = 0; r < 4; ++r) {
            float s = se[r];
            s += __shfl_xor(s, 1);
            s += __shfl_xor(s, 2);
            s += __shfl_xor(s, 4);
            s += __shfl_xor(s, 8);
            if (l15 == 0) mlL[h * 16 + quad * 4 + r] = 1.f / s;
        }
    }
    __syncthreads();

    float invl[2][4];
#pragma unroll
    for (int hh = 0; hh < 2; ++hh)
#pragma unroll
        for (int r = 0; r < 4; ++r) invl[hh][r] = mlL[(h0 + hh) * 16 + quad * 4 + r];

    floatx4 o[2][4];
#pragma unroll
    for (int hh = 0; hh < 2; ++hh)
#pragma unroll
        for (int dt = 0; dt < 4; ++dt) o[hh][dt] = (floatx4){0.f, 0.f, 0.f, 0.f};

    // ---- pass 2: stream 32-wide j tiles ----
    for (int jt = 0; jt < 32; ++jt) {
        const int j0 = jt * 32;
        // (a) S -> w -> Buf1[p][h]
#pragma unroll
        for (int hh = 0; hh < 2; ++hh) {
            int h = h0 + hh;
#pragma unroll
            for (int ns = 0; ns < 2; ++ns) {
                const bf16* kp = Kbase + (size_t)(j0 + ns * 16 + l15) * 1024 + h * 64 + quad * 8;
                floatx4 c = {0.f, 0.f, 0.f, 0.f};
                c = MFMA_BF16(qa[hh][0], *(const bf16x8*)kp, c);
                c = MFMA_BF16(qa[hh][1], *(const bf16x8*)(kp + 32), c);
#pragma unroll
                for (int r = 0; r < 4; ++r) {
                    float w = __expf(c[r] * scale) * invl[hh][r];
                    int i = quad * 4 + r, jl = ns * 16 + l15;
                    Buf1[(i * 32 + jl) * 40 + h] = (bf16)w;
                }
            }
        }
        __syncthreads();
        // (c) talking-heads mix + LayerNorm over heads
#pragma unroll
        for (int grp = 0; grp < 4; ++grp) {
            int gi = wv * 4 + grp;          // 0..31: i = gi>>1, jb = (gi&1)*16
            int ig = gi >> 1, jb = (gi & 1) * 16;
            bf16x8 a = *(bf16x8*)&Buf1[(ig * 32 + jb + l15) * 40 + quad * 8];
            floatx4 c = {0.f, 0.f, 0.f, 0.f};
            c = MFMA_BF16(a, wtf, c);       // C[row=jl-jb][col=g]
#pragma unroll
            for (int r = 0; r < 4; ++r) {
                float x = c[r];
                float s1 = x, s2 = x * x;
                s1 += __shfl_xor(s1, 1); s2 += __shfl_xor(s2, 1);
                s1 += __shfl_xor(s1, 2); s2 += __shfl_xor(s2, 2);
                s1 += __shfl_xor(s1, 4); s2 += __shfl_xor(s2, 4);
                s1 += __shfl_xor(s1, 8); s2 += __shfl_xor(s2, 8);
                float mu = s1 * 0.0625f;
                float var = s2 * 0.0625f - mu * mu;
                float w2 = (x - mu) * rsqrtf(var + 1e-5f) * gamma_l + beta_l;
                int jl = jb + quad * 4 + r;
                Buf2[l15 * 648 + ig * 40 + jl] = (bf16)w2;
            }
        }
        __syncthreads();
        // (d) PV: O[i,d] += P[i,jl] * V[jl,d]
#pragma unroll
        for (int hh = 0; hh < 2; ++hh) {
            int g = h0 + hh;
            bf16x8 a = *(bf16x8*)&Buf2[g * 648 + l15 * 40 + quad * 8];
#pragma unroll
            for (int dt = 0; dt < 4; ++dt) {
                const bf16* vp = Vbase + (size_t)(g * 64 + dt * 16 + l15) * 1024 + j0 + quad * 8;
                o[hh][dt] = MFMA_BF16(a, *(const bf16x8*)vp, o[hh][dt]);
            }
        }
        // next-iteration barriers protect Buf1/Buf2 reuse
    }

    // epilogue: out[b, i0+i, g*64 + dt*16 + l15]
#pragma unroll
    for (int hh = 0; hh < 2; ++hh) {
        int g = h0 + hh;
#pragma unroll
        for (int dt = 0; dt < 4; ++dt)
#pragma unroll
            for (int r = 0; r < 4; ++r) {
                int i = quad * 4 + r;
                out[(size_t)(b * 1024 + i0 + i) * 1024 + g * 64 + dt * 16 + l15] = o[hh][dt][r];
            }
    }
}

extern "C" void kernel_launch(void* const* d_in, const int* in_sizes, int n_in,
                              void* d_out, int out_size, void* d_ws, size_t ws_size,
                              hipStream_t stream) {
    const float* x     = (const float*)d_in[0];
    const float* ctx   = (const float*)d_in[1];
    const float* Wq    = (const float*)d_in[2];
    const float* Wkv   = (const float*)d_in[3];
    const float* Wt    = (const float*)d_in[4];
    const float* gamma = (const float*)d_in[5];
    const float* beta  = (const float*)d_in[6];
    float* out = (float*)d_out;

    // workspace layout (bf16): Q[4096,1024] | K[4096,1024] | Vt[b,h,d,j] -> 24 MB
    bf16* Qb = (bf16*)d_ws;
    bf16* Kb = Qb + (size_t)4096 * 1024;
    bf16* Vt = Kb + (size_t)4096 * 1024;

    gemm_q<<<dim3(16, 64), 256, 0, stream>>>(x, Wq, Qb);
    gemm_kv<<<dim3(32, 64), 256, 0, stream>>>(ctx, Wkv, Kb, Vt);
    attn_kernel<<<dim3(64, 4), 512, 0, stream>>>(Qb, Kb, Vt, Wt, gamma, beta, out);
}

// Round 2
// 356.221 us; speedup vs baseline: 1.4987x; 1.4987x over previous
//
#include <hip/hip_runtime.h>
#include <hip/hip_bf16.h>

typedef __bf16 bf16;
typedef bf16 bf16x2 __attribute__((ext_vector_type(2)));
typedef bf16 bf16x4 __attribute__((ext_vector_type(4)));
typedef bf16 bf16x8 __attribute__((ext_vector_type(8)));
typedef float floatx4 __attribute__((ext_vector_type(4)));

#define MFMA_BF16(a, b, c) __builtin_amdgcn_mfma_f32_16x16x32_bf16((a), (b), (c), 0, 0, 0)

// ---------------------------------------------------------------------------
// fp32 -> bf16 elementwise convert (8 els/thread)
// ---------------------------------------------------------------------------
__global__ __launch_bounds__(256) void cvt_kernel(const float* __restrict__ in,
                                                  bf16* __restrict__ out, int n8) {
    int idx = blockIdx.x * 256 + threadIdx.x;
    if (idx >= n8) return;
    const float* src = in + (size_t)idx * 8;
    float4 f0 = *(const float4*)src;
    float4 f1 = *(const float4*)(src + 4);
    bf16x8 v = {(bf16)f0.x, (bf16)f0.y, (bf16)f0.z, (bf16)f0.w,
                (bf16)f1.x, (bf16)f1.y, (bf16)f1.z, (bf16)f1.w};
    *(bf16x8*)(out + (size_t)idx * 8) = v;
}

// ---------------------------------------------------------------------------
// fp32 [R][C] -> bf16 [C][R] transpose (32x32 LDS tiles)
// ---------------------------------------------------------------------------
__global__ __launch_bounds__(256) void trans_kernel(const float* __restrict__ in,
                                                    bf16* __restrict__ out, int R, int C) {
    __shared__ float tile[32][33];
    const int t = threadIdx.x;
    const int r0 = blockIdx.y * 32, c0 = blockIdx.x * 32;
    int r = t >> 3, c4 = (t & 7) * 4;
    float4 v = *(const float4*)&in[(size_t)(r0 + r) * C + c0 + c4];
    tile[r][c4 + 0] = v.x; tile[r][c4 + 1] = v.y;
    tile[r][c4 + 2] = v.z; tile[r][c4 + 3] = v.w;
    __syncthreads();
    int rp = t >> 3, cp = (t & 7) * 4;
    bf16x4 w = {(bf16)tile[cp + 0][rp], (bf16)tile[cp + 1][rp],
                (bf16)tile[cp + 2][rp], (bf16)tile[cp + 3][rp]};
    *(bf16x4*)&out[(size_t)(c0 + rp) * R + r0 + cp] = w;
}

// ---------------------------------------------------------------------------
// bf16 [4096][1024] (rows=b*1024+j, cols=h*64+d) -> Vt[b][h][d][j]
// ---------------------------------------------------------------------------
__global__ __launch_bounds__(256) void vtrans_kernel(const bf16* __restrict__ in,
                                                     bf16* __restrict__ out) {
    __shared__ bf16 tile[32][36];
    const int t = threadIdx.x;
    const int r0 = blockIdx.y * 32, c0 = blockIdx.x * 32;  // r=m, c=h*64+d
    int r = t >> 3, c4 = (t & 7) * 4;
    bf16x4 v = *(const bf16x4*)&in[(size_t)(r0 + r) * 1024 + c0 + c4];
    tile[r][c4 + 0] = v[0]; tile[r][c4 + 1] = v[1];
    tile[r][c4 + 2] = v[2]; tile[r][c4 + 3] = v[3];
    __syncthreads();
    int rp = t >> 3, cp = (t & 7) * 4;
    int hd = c0 + rp;                 // (h*64+d)
    int b = r0 >> 10, j = (r0 & 1023) + cp;
    bf16x4 w = {tile[cp + 0][rp], tile[cp + 1][rp], tile[cp + 2][rp], tile[cp + 3][rp]};
    *(bf16x4*)&out[(size_t)(b * 1024 + hd) * 1024 + j] = w;
}

// ---------------------------------------------------------------------------
// m93-style 128x128 GEMM, BK=32, 256 threads (4 waves, 64x64/wave, 4x4 MFMA).
// A [M][1024] bf16 row-major; B [N][1024] bf16 (pre-transposed, n-major).
// MODE 0: C[m*N+n].  MODE 1 (KV): n<1024 -> C (K), n>=1024 -> V [m][n-1024].
// ---------------------------------------------------------------------------
template <int MODE>
__global__ __launch_bounds__(256) void gemm128(const bf16* __restrict__ A,
                                               const bf16* __restrict__ B,
                                               bf16* __restrict__ C,
                                               bf16* __restrict__ V, int N) {
    __shared__ bf16 As[128 * 40];
    __shared__ bf16 Bs[128 * 40];
    const int t = threadIdx.x;
    const int wv = t >> 6, lane = t & 63, quad = lane >> 4, l15 = lane & 15;
    const int wr = wv >> 1, wc = wv & 1;
    const int m0 = blockIdx.y * 128, n0 = blockIdx.x * 128;
    const int ra = t >> 1, kc = (t & 1) * 16;

    floatx4 acc[4][4] = {};

    for (int k0 = 0; k0 < 1024; k0 += 32) {
        bf16x8 a0 = *(const bf16x8*)&A[(size_t)(m0 + ra) * 1024 + k0 + kc];
        bf16x8 a1 = *(const bf16x8*)&A[(size_t)(m0 + ra) * 1024 + k0 + kc + 8];
        bf16x8 b0 = *(const bf16x8*)&B[(size_t)(n0 + ra) * 1024 + k0 + kc];
        bf16x8 b1 = *(const bf16x8*)&B[(size_t)(n0 + ra) * 1024 + k0 + kc + 8];
        __syncthreads();
        *(bf16x8*)&As[ra * 40 + kc] = a0;
        *(bf16x8*)&As[ra * 40 + kc + 8] = a1;
        *(bf16x8*)&Bs[ra * 40 + kc] = b0;
        *(bf16x8*)&Bs[ra * 40 + kc + 8] = b1;
        __syncthreads();
        bf16x8 af[4], bfr[4];
#pragma unroll
        for (int mt = 0; mt < 4; ++mt)
            af[mt] = *(bf16x8*)&As[(wr * 64 + mt * 16 + l15) * 40 + quad * 8];
#pragma unroll
        for (int nt = 0; nt < 4; ++nt)
            bfr[nt] = *(bf16x8*)&Bs[(wc * 64 + nt * 16 + l15) * 40 + quad * 8];
#pragma unroll
        for (int mt = 0; mt < 4; ++mt)
#pragma unroll
            for (int nt = 0; nt < 4; ++nt)
                acc[mt][nt] = MFMA_BF16(af[mt], bfr[nt], acc[mt][nt]);
    }
#pragma unroll
    for (int mt = 0; mt < 4; ++mt)
#pragma unroll
        for (int nt = 0; nt < 4; ++nt)
#pragma unroll
            for (int r = 0; r < 4; ++r) {
                int m = m0 + wr * 64 + mt * 16 + quad * 4 + r;
                int n = n0 + wc * 64 + nt * 16 + l15;
                bf16 val = (bf16)acc[mt][nt][r];
                if (MODE == 0) {
                    C[(size_t)m * N + n] = val;
                } else {
                    if (n < 1024) C[(size_t)m * 1024 + n] = val;
                    else          V[(size_t)m * 1024 + (n - 1024)] = val;
                }
            }
}

// ---------------------------------------------------------------------------
// Softmax denominators: L[b][h][i] = sum_j exp(q.k*scale).
// grid (i32-tiles=32, b=4, jsplit=4), 256 thr = 4 waves, 4 heads/wave.
// ---------------------------------------------------------------------------
__global__ __launch_bounds__(256) void denom_kernel(const bf16* __restrict__ Qb,
                                                    const bf16* __restrict__ Kb,
                                                    float* __restrict__ L) {
    const int t = threadIdx.x;
    const int wv = t >> 6, lane = t & 63, quad = lane >> 4, l15 = lane & 15;
    const int i0 = blockIdx.x * 32, b = blockIdx.y, jz = blockIdx.z;
    const float scale = 0.125f;

    bf16x8 qa[4][2][2];
#pragma unroll
    for (int hh = 0; hh < 4; ++hh)
#pragma unroll
        for (int it = 0; it < 2; ++it) {
            const bf16* qp = Qb + (size_t)(b * 1024 + i0 + it * 16 + l15) * 1024 +
                             (wv * 4 + hh) * 64 + quad * 8;
            qa[hh][it][0] = *(const bf16x8*)qp;
            qa[hh][it][1] = *(const bf16x8*)(qp + 32);
        }
    floatx4 se[4][2] = {};
    const bf16* Kbase = Kb + (size_t)b * 1024 * 1024;

    for (int jt = 0; jt < 16; ++jt) {
        int j = jz * 256 + jt * 16 + l15;
#pragma unroll
        for (int hh = 0; hh < 4; ++hh) {
            const bf16* kp = Kbase + (size_t)j * 1024 + (wv * 4 + hh) * 64 + quad * 8;
            bf16x8 k0 = *(const bf16x8*)kp;
            bf16x8 k1 = *(const bf16x8*)(kp + 32);
#pragma unroll
            for (int it = 0; it < 2; ++it) {
                floatx4 c = {0.f, 0.f, 0.f, 0.f};
                c = MFMA_BF16(qa[hh][it][0], k0, c);
                c = MFMA_BF16(qa[hh][it][1], k1, c);
#pragma unroll
                for (int r = 0; r < 4; ++r) se[hh][it][r] += __expf(c[r] * scale);
            }
        }
    }
#pragma unroll
    for (int hh = 0; hh < 4; ++hh)
#pragma unroll
        for (int it = 0; it < 2; ++it)
#pragma unroll
            for (int r = 0; r < 4; ++r) {
                float s = se[hh][it][r];
                s += __shfl_xor(s, 1); s += __shfl_xor(s, 2);
                s += __shfl_xor(s, 4); s += __shfl_xor(s, 8);
                if (l15 == 0)
                    atomicAdd(&L[(size_t)(b * 16 + wv * 4 + hh) * 1024 + i0 + it * 16 +
                                 quad * 4 + r], s);
            }
}

// ---------------------------------------------------------------------------
// Main fused attention. grid (i16-tiles=64, b=4, jsplit=2), 512 thr = 8 waves,
// 2 heads/wave. Per 32-wide j-tile: S (MFMA) -> w=exp*invl -> Buf1 ->
// centered-Wt mix (MFMA, C[g][point]) + LN (2 shuffles) -> Buf2 -> PV (MFMA).
// Partial O atomicAdd'ed into out (out pre-zeroed).
// ---------------------------------------------------------------------------
__global__ __launch_bounds__(512, 4) void attn_kernel(const bf16* __restrict__ Qb,
                                                      const bf16* __restrict__ Kb,
                                                      const bf16* __restrict__ Vt,
                                                      const float* __restrict__ L,
                                                      const float* __restrict__ Wt,
                                                      const float* __restrict__ gamma,
                                                      const float* __restrict__ beta,
                                                      float* __restrict__ out) {
    __shared__ bf16 Buf1[512 * 20];        // [point p=i*32+jl][16 h + 4 pad]
    __shared__ bf16 Buf2[16 * 648];        // [g][i*40 + jl], strides tuned for banks
    __shared__ __align__(16) bf16 Zbuf[8]; // zero region for mix k>=16

    const int t = threadIdx.x;
    const int wv = t >> 6, lane = t & 63, quad = lane >> 4, l15 = lane & 15;
    const int i0 = blockIdx.x * 16, b = blockIdx.y, jz = blockIdx.z;
    const float scale = 0.125f;

    if (t < 8) Zbuf[t] = (bf16)0.f;

    // A-frag of centered Wt^T: a_wt[jj] = Wt_c[k=quad*8+jj][g=l15], 0 for k>=16.
    bf16x8 a_wt;
#pragma unroll
    for (int jj = 0; jj < 8; ++jj) {
        int k = quad * 8 + jj;
        float v = 0.f;
        if (k < 16) {
            float s = 0.f;
            for (int g = 0; g < 16; ++g) s += Wt[k * 16 + g];
            v = Wt[k * 16 + l15] - s * 0.0625f;
        }
        a_wt[jj] = (bf16)v;
    }
    float gq[4], bq[4];
#pragma unroll
    for (int r = 0; r < 4; ++r) { gq[r] = gamma[quad * 4 + r]; bq[r] = beta[quad * 4 + r]; }

    bf16x8 qa[2][2];
    float invl[2][4];
#pragma unroll
    for (int hh = 0; hh < 2; ++hh) {
        int h = wv * 2 + hh;
        const bf16* qp = Qb + (size_t)(b * 1024 + i0 + l15) * 1024 + h * 64 + quad * 8;
        qa[hh][0] = *(const bf16x8*)qp;
        qa[hh][1] = *(const bf16x8*)(qp + 32);
#pragma unroll
        for (int r = 0; r < 4; ++r)
            invl[hh][r] = 1.f / L[(size_t)(b * 16 + h) * 1024 + i0 + quad * 4 + r];
    }

    const bf16* Kbase = Kb + (size_t)b * 1024 * 1024;
    const bf16* Vbase = Vt + (size_t)b * 16 * 64 * 1024;
    floatx4 o[2][4] = {};

    for (int jt = 0; jt < 16; ++jt) {
        const int j0 = jz * 512 + jt * 32;
        // (a) S -> w -> Buf1 (packed bf16x2 for the wave's head pair)
#pragma unroll
        for (int ns = 0; ns < 2; ++ns) {
            floatx4 cw[2];
#pragma unroll
            for (int hh = 0; hh < 2; ++hh) {
                int h = wv * 2 + hh;
                const bf16* kp = Kbase + (size_t)(j0 + ns * 16 + l15) * 1024 + h * 64 + quad * 8;
                floatx4 c = {0.f, 0.f, 0.f, 0.f};
                c = MFMA_BF16(qa[hh][0], *(const bf16x8*)kp, c);
                c = MFMA_BF16(qa[hh][1], *(const bf16x8*)(kp + 32), c);
                cw[hh] = c;
            }
#pragma unroll
            for (int r = 0; r < 4; ++r) {
                bf16x2 pk = {(bf16)(__expf(cw[0][r] * scale) * invl[0][r]),
                             (bf16)(__expf(cw[1][r] * scale) * invl[1][r])};
                *(bf16x2*)&Buf1[((quad * 4 + r) * 32 + ns * 16 + l15) * 20 + wv * 2] = pk;
            }
        }
        __syncthreads();
        // (b) mix (C[g][point]) + LN over g (mean is exactly 0 by centering)
#pragma unroll
        for (int grp = 0; grp < 4; ++grp) {
            int gi = wv * 4 + grp, ig = gi >> 1, jb = (gi & 1) * 16;
            int p = ig * 32 + jb + l15;
            const bf16* src = (quad < 2) ? &Buf1[p * 20 + quad * 8] : Zbuf;
            floatx4 c = {0.f, 0.f, 0.f, 0.f};
            c = MFMA_BF16(a_wt, *(const bf16x8*)src, c);
            float s2 = c[0] * c[0] + c[1] * c[1] + c[2] * c[2] + c[3] * c[3];
            s2 += __shfl_xor(s2, 16);
            s2 += __shfl_xor(s2, 32);
            float rs = rsqrtf(s2 * 0.0625f + 1e-5f);
#pragma unroll
            for (int r = 0; r < 4; ++r) {
                float w2 = c[r] * rs * gq[r] + bq[r];
                Buf2[(quad * 4 + r) * 648 + ig * 40 + jb + l15] = (bf16)w2;
            }
        }
        __syncthreads();
        // (c) PV: O[i][d] += w2[i][jl] * V[jl][d]
#pragma unroll
        for (int hh = 0; hh < 2; ++hh) {
            int g = wv * 2 + hh;
            bf16x8 a = *(bf16x8*)&Buf2[g * 648 + l15 * 40 + quad * 8];
#pragma unroll
            for (int dt = 0; dt < 4; ++dt) {
                const bf16* vp = Vbase + (size_t)(g * 64 + dt * 16 + l15) * 1024 + j0 + quad * 8;
                o[hh][dt] = MFMA_BF16(a, *(const bf16x8*)vp, o[hh][dt]);
            }
        }
    }
#pragma unroll
    for (int hh = 0; hh < 2; ++hh) {
        int g = wv * 2 + hh;
#pragma unroll
        for (int dt = 0; dt < 4; ++dt)
#pragma unroll
            for (int r = 0; r < 4; ++r)
                atomicAdd(&out[(size_t)(b * 1024 + i0 + quad * 4 + r) * 1024 +
                               g * 64 + dt * 16 + l15], o[hh][dt][r]);
    }
}

extern "C" void kernel_launch(void* const* d_in, const int* in_sizes, int n_in,
                              void* d_out, int out_size, void* d_ws, size_t ws_size,
                              hipStream_t stream) {
    const float* x     = (const float*)d_in[0];
    const float* ctx   = (const float*)d_in[1];
    const float* Wq    = (const float*)d_in[2];
    const float* Wkv   = (const float*)d_in[3];
    const float* Wt    = (const float*)d_in[4];
    const float* gamma = (const float*)d_in[5];
    const float* beta  = (const float*)d_in[6];
    float* out = (float*)d_out;

    // ws layout (bf16 els): xb 4M | ctxb 4M | WqT 1M | WkvT 2M | Qb 4M | Kb 4M |
    //                       Vr 4M | Vt 4M | L (64K fp32)   => ~54.25 MB
    bf16* xb   = (bf16*)d_ws;
    bf16* cb   = xb + (size_t)4 * 1024 * 1024;
    bf16* WqT  = cb + (size_t)4 * 1024 * 1024;
    bf16* WkvT = WqT + (size_t)1024 * 1024;
    bf16* Qb   = WkvT + (size_t)2048 * 1024;
    bf16* Kb   = Qb + (size_t)4 * 1024 * 1024;
    bf16* Vr   = Kb + (size_t)4 * 1024 * 1024;
    bf16* Vt   = Vr + (size_t)4 * 1024 * 1024;
    float* L   = (float*)(Vt + (size_t)4 * 1024 * 1024);

    hipMemsetAsync(L, 0, (size_t)4 * 16 * 1024 * sizeof(float), stream);
    hipMemsetAsync(out, 0, (size_t)out_size * sizeof(float), stream);

    cvt_kernel<<<2048, 256, 0, stream>>>(x, xb, 524288);
    cvt_kernel<<<2048, 256, 0, stream>>>(ctx, cb, 524288);
    trans_kernel<<<dim3(32, 32), 256, 0, stream>>>(Wq, WqT, 1024, 1024);
    trans_kernel<<<dim3(64, 32), 256, 0, stream>>>(Wkv, WkvT, 1024, 2048);

    gemm128<0><<<dim3(8, 32), 256, 0, stream>>>(xb, WqT, Qb, nullptr, 1024);
    gemm128<1><<<dim3(16, 32), 256, 0, stream>>>(cb, WkvT, Kb, Vr, 2048);
    vtrans_kernel<<<dim3(32, 128), 256, 0, stream>>>(Vr, Vt);

    denom_kernel<<<dim3(32, 4, 4), 256, 0, stream>>>(Qb, Kb, L);
    attn_kernel<<<dim3(64, 4, 2), 512, 0, stream>>>(Qb, Kb, Vt, L, Wt, gamma, beta, out);
}